// Round 9
// baseline (100.726 us; speedup 1.0000x reference)
//
#include <hip/hip_runtime.h>

// ConvCRF forward, MI355X — round 24: channel-pair split tap engine.
// R23 post-mortem: kernel ~38-39us (below the harness's own 41us ws-poison
// fills). Remaining in-loop cost = tap engine: b128 (irreducible 4-way, 8cy)
// + 6 pk_fma + 2 weight cvts per tap on only 2 waves/SIMD.
// R24 restructure: split each channel QUAD across 2 threads (channel PAIRS).
//  - 1024 thr = 10 groups x 100 px = 16 waves/CU (4/SIMD, 2x TLP).
//  - sm halo: 10 float2 planes, stride 26 f2 -> ds_read_b64 with bankpair
//    = (px+K) mod 16: exact 2-way = FREE (m136), vs b128's 4-way floor.
//  - weights stored f32 pairs in LDS (39.2KB; total ~76KB, 1 block/CU by
//    design): per tap = 2x b64 + 3 pk_fma, ZERO cvts (was 6 pk_fma + 2 cvt).
//    f32 weights also improve precision vs f16-rounded.
//  - per-channel accumulation order unchanged (t ascending) -> numerics
//    match or improve.
//  - gsm exchange becomes u32/channel-pair (f16x2), same bytes, same
//    drain-before-epoch ordering proof.
// Carried: tag epochs + watchdog, early sm0 publish, neighbor-only sync,
// rgb prefetch under M, 2-exp taps (now ~5/thread), partial bilateral norms,
// separable spatial norm, ring staging + f32 interior self-write, diag fast
// path, O(19)/entry M prologue, grid (16,16) = 1 block/CU.

typedef __attribute__((ext_vector_type(2))) _Float16 half2f;
typedef __attribute__((ext_vector_type(2))) float float2v;

#define HH 160
#define WW 160
#define NPIX (HH*WW)
#define NC 19
#define NG 10
#define SPAN 3
#define TR 10
#define TC 10
#define NPXT 100
#define LR 16              // TR + 2*SPAN
#define LC 16              // TC + 2*SPAN
#define LCP2 26            // sm plane row stride (float2 units) — 2-way-free
#define PSTRIDE (LR*LCP2)  // 416
#define LCP4 18            // rgb halo row stride (float4 units)
#define HSTR4 (LR*LCP4)    // 288
#define NRING 156          // 16x16 halo minus 10x10 interior
#define NTHR 1024
#define NACT 1000          // 10 groups x 100 px
#define EPSF 1e-20f

// epoch word: hi16 = tag, lo16 = seq. hi16 != tag -> seq 0. Tag bytes differ
// (0x5E vs 0xED) so no byte-uniform poison aliases it.
#define EPTAG   0x5EED0000u
#define EPMASK  0xFFFF0000u
#define EPW(b)  (32 + (b)*32)

// shm layout (bytes):
//   sm planes : 0 .. 33280     (10 x 416 float2, per-iter)
//   rgbL      : 0 .. 9216      (2 x 288 float4, prologue only, overlays planes)
//   PN        : 9216 .. 17216  (1000 float2 partial norms, prologue only)
//   accF      : 0 .. 24000     (60 x 100 f32, non-diag epilogue, overlays)
//   wbF       : 33280 .. 72480 (49 x 100 float2 f32 weights, whole kernel)
#define PN_OFF  9216
#define OFF_WB  33280
#define SHM_SZ  72480

__device__ __forceinline__ float fast_rcp(float x) { return __builtin_amdgcn_rcpf(x); }

__device__ __forceinline__ float smx0(float q0, float q1) {
    const float m  = fmaxf(q0, q1);
    const float e0 = __expf(q0 - m);
    const float e1 = __expf(q1 - m);
    return e0 * fast_rcp(e0 + e1);
}

__device__ __forceinline__ unsigned ep_decode(unsigned w) {
    return ((w & EPMASK) == EPTAG) ? (w & 0xFFFFu) : 0u;
}

__global__ void __launch_bounds__(NTHR) crf_kernel(
        const float* __restrict__ u,
        const float* __restrict__ rgb,
        const float* __restrict__ sw,
        const float* __restrict__ bw,
        const float* __restrict__ compat,
        unsigned* __restrict__ gsmA,   // ping-pong sm0 fields (f16x2 / ch-pair)
        unsigned* __restrict__ gsmB,
        unsigned* __restrict__ bar,
        float* __restrict__ out) {
    __shared__ __align__(16) char shm[SHM_SZ];
    __shared__ float Msh[960];                   // 20x48 rows [Ms|Mb|RS|pad]
    __shared__ float rowsum[NC];
    __shared__ int   diagflag;
    float4*   rgbL = (float4*)shm;               // prologue only
    float2v*  smP  = (float2v*)shm;              // 10 sm planes (f32 pairs)
    float*    accF = (float*)shm;                // non-diag epilogue
    float2v*  wbF  = (float2v*)(shm + OFF_WB);   // f32 weight pairs

    constexpr float WSPC[49] = {
        0.36787944f,0.48567179f,0.57375342f,0.60653066f,0.57375342f,0.48567179f,0.36787944f,
        0.48567179f,0.64118039f,0.75746513f,0.80073740f,0.75746513f,0.64118039f,0.48567179f,
        0.57375342f,0.75746513f,0.89483932f,0.94595947f,0.89483932f,0.75746513f,0.57375342f,
        0.60653066f,0.80073740f,0.94595947f,1.00000000f,0.94595947f,0.80073740f,0.60653066f,
        0.57375342f,0.75746513f,0.89483932f,0.94595947f,0.89483932f,0.75746513f,0.57375342f,
        0.48567179f,0.64118039f,0.75746513f,0.80073740f,0.75746513f,0.64118039f,0.48567179f,
        0.36787944f,0.48567179f,0.57375342f,0.60653066f,0.57375342f,0.48567179f,0.36787944f };

    const int tid = threadIdx.x;
    const bool act = (tid < NACT);
    const int g   = tid / NPXT;                 // 0..9 (10 for idle tail, guarded)
    const int px  = tid - g * NPXT;             // 0..99
    const int r   = px / TC, c = px - r * TC;   // 10x10 tile coords
    const int ti0 = blockIdx.y * TR, tj0 = blockIdx.x * TC;
    const int gp  = (ti0 + r) * WW + (tj0 + c);
    const int ctr2 = (r + SPAN) * LCP2 + (c + SPAN);   // sm plane center (f2)
    const int ctr4 = (r + SPAN) * LCP4 + (c + SPAN);   // rgb halo center (f4)
    const int bid = blockIdx.y * 16 + blockIdx.x;      // grid (16, 16)

    // neighbor epochs to wait on (pad missing neighbors with own bid)
    int nb[8];
    {
        const int bx = blockIdx.x, by = blockIdx.y;
        int k = 0;
        #pragma unroll
        for (int dy2 = -1; dy2 <= 1; ++dy2)
            #pragma unroll
            for (int dx2 = -1; dx2 <= 1; ++dx2) {
                if (dx2 == 0 && dy2 == 0) continue;
                const int nx = bx + dx2, ny = by + dy2;
                nb[k++] = ((unsigned)nx < 16u && (unsigned)ny < 16u) ? (ny*16 + nx) : bid;
            }
    }

    if (tid == 0) diagflag = 1;

    // ---- earliest possible: own unaries -> sm0 -> publish (iteration 0) ----
    float uv0[2], uv1[2];
    float smv[2];
    if (act) {
        #pragma unroll
        for (int i = 0; i < 2; ++i) {
            const int ch = 2*g + i;
            uv0[i] = (ch < NC) ? u[(size_t)gp * NC + ch] : 0.0f;
            uv1[i] = (ch < NC) ? u[((size_t)NPIX + gp) * NC + ch] : 0.0f;
            smv[i] = smx0(uv0[i], uv1[i]);
        }
        half2f hp = {(_Float16)smv[0], (_Float16)smv[1]};
        unsigned u32; __builtin_memcpy(&u32, &hp, 4);
        __hip_atomic_store(&gsmA[g * NPIX + gp], u32,
                           __ATOMIC_RELAXED, __HIP_MEMORY_SCOPE_AGENT);
    }

    if (tid < NC) {
        float rs = 0.0f;
        for (int cb = 0; cb < NC; ++cb) rs += sw[tid*NC + cb] + bw[tid*NC + cb];
        rowsum[tid] = rs;
    }
    __syncthreads();             // drains ALL waves' sm0 publishes (vmcnt 0)
    if (tid == 0)                // epoch visible to neighbors during prologue
        __hip_atomic_store(&bar[EPW(bid)], EPTAG | 1u,
                           __ATOMIC_RELAXED, __HIP_MEMORY_SCOPE_AGENT);

    // ---- rgb halo prefetch: 1 elem for tid<512 (2 batches x 256 positions),
    //      issued BEFORE the M compute so the load latency hides under it ----
    float4 rv;
    int rgb_idx = -1;
    if (tid < 512) {
        const int bb = tid >> 8, pos = tid & 255;
        const int hr = pos >> 4, hc = pos & 15;
        const int yi = ti0 - SPAN + hr, xj = tj0 - SPAN + hc;
        rv = make_float4(0.f, 0.f, 0.f, 0.f);
        if ((unsigned)yi < HH && (unsigned)xj < WW) {
            const float* p = rgb + ((size_t)(bb * NPIX) + yi * WW + xj) * 3;
            rv = make_float4(p[0]*(1.f/160.f), p[1]*(1.f/160.f), p[2]*(1.f/160.f), 1.f);
        }
        rgb_idx = bb * HSTR4 + hr * LCP4 + hc;
    }

    // ---- phase 0: M = [compat@sw | compat@bw | RS] into LDS, O(19)/entry ----
    for (int e = tid; e < 960; e += NTHR) {
        const int k = e / 48, cc2 = e % 48;
        float acc = 0.0f;
        if (k < NC) {
            if (cc2 < NC) {
                for (int j = 0; j < NC; ++j) acc += compat[k*NC + j] * sw[j*NC + cc2];
            } else if (cc2 >= 20 && cc2 < 20 + NC) {
                const int cb = cc2 - 20;
                for (int j = 0; j < NC; ++j) acc += compat[k*NC + j] * bw[j*NC + cb];
            } else if (cc2 == 40) {
                for (int j = 0; j < NC; ++j) acc += compat[k*NC + j] * rowsum[j];
            }
        }
        Msh[e] = acc;
        bool off = false;
        if (k < NC) {
            if (cc2 < NC && cc2 != k && acc != 0.0f) off = true;
            if (cc2 >= 20 && cc2 < 20 + NC && (cc2 - 20) != k && acc != 0.0f) off = true;
        }
        if (off) atomicAnd(&diagflag, 0);
    }

    // ---- phase 1: rgb halo writeback (waits on the prefetch here) ----
    if (rgb_idx >= 0) rgbL[rgb_idx] = rv;
    __syncthreads();             // covers Msh + rgbL

    float dsv[2], dbv[2];
    if (act) {
        #pragma unroll
        for (int i = 0; i < 2; ++i) {
            const int k = 2*g + i;           // k <= 19 < 20 rows
            dsv[i] = Msh[k * 48 + k];
            dbv[i] = Msh[k * 48 + 20 + k];
        }
    }
    const bool isdiag = (diagflag != 0);

    // ---- phase 2a: bilateral weights (~5 taps per group) -> f32 LDS pairs,
    //      spatial exponent folded into the batch exponent (2 exps/tap),
    //      partial norms accumulated on the fly ----
    if (act) {
        const float4 cv0 = rgbL[ctr4];
        const float4 cv1 = rgbL[HSTR4 + ctr4];
        const int tb = 5 * g;
        const int ntap = (g == 9) ? 4 : 5;
        float pn0 = 0.f, pn1 = 0.f;
        for (int i = 0; i < ntap; ++i) {
            const int t = tb + i;
            const int dx = t / 7 - SPAN, dy = t % 7 - SPAN;
            const int n = ctr4 + dx * LCP4 + dy;
            const float4 nv0 = rgbL[n];
            const float4 nv1 = rgbL[HSTR4 + n];
            const float spc = (float)(dx*dx + dy*dy) * (-1.f/18.f);
            const float dr0 = cv0.x-nv0.x, dg0 = cv0.y-nv0.y, db0 = cv0.z-nv0.z;
            const float dr1 = cv1.x-nv1.x, dg1 = cv1.y-nv1.y, db1 = cv1.z-nv1.z;
            const float d0 = dr0*dr0 + dg0*dg0 + db0*db0;
            const float d1 = dr1*dr1 + dg1*dg1 + db1*db1;
            const float wb0 = nv0.w * __expf(fmaf(d0, -0.5f, spc));
            const float wb1 = nv0.w * __expf(fmaf(d1, -0.5f, spc));
            wbF[t * NPXT + px] = (float2v){wb0, wb1};
            pn0 += wb0; pn1 += wb1;
        }
        *(float2*)(shm + PN_OFF + (g * NPXT + px) * 8) = make_float2(pn0, pn1);
    }
    __syncthreads();

    // ---- phase 2b: inverse norms — 10-term partial reduce + separable sn ----
    float snI, bnI0, bnI1;
    if (act) {
        float bn0 = 0.f, bn1 = 0.f;
        #pragma unroll
        for (int g2 = 0; g2 < NG; ++g2) {
            const float2 p = *(const float2*)(shm + PN_OFF + (g2 * NPXT + px) * 8);
            bn0 += p.x; bn1 += p.y;
        }
        const int rg = ti0 + r, cg = tj0 + c;
        float Rr = 5.70645506f, Cc = 5.70645506f;
        Rr -= (rg < 3   ? 0.60653066f : 0.f) + (rg < 2   ? 0.80073740f : 0.f)
            + (rg < 1   ? 0.94595947f : 0.f) + (rg > 156 ? 0.60653066f : 0.f)
            + (rg > 157 ? 0.80073740f : 0.f) + (rg > 158 ? 0.94595947f : 0.f);
        Cc -= (cg < 3   ? 0.60653066f : 0.f) + (cg < 2   ? 0.80073740f : 0.f)
            + (cg < 1   ? 0.94595947f : 0.f) + (cg > 156 ? 0.60653066f : 0.f)
            + (cg > 157 ? 0.80073740f : 0.f) + (cg > 158 ? 0.94595947f : 0.f);
        snI  = fast_rcp(Rr * Cc + EPSF);
        bnI0 = fast_rcp(bn0 + EPSF);
        bnI1 = fast_rcp(bn1 + EPSF);
    }

    for (int it = 0; it < 5; ++it) {
        // B1: drains this iter's tail publishes (vmcnt 0) + all waves past
        // previous LDS reads -> plane region reusable
        __syncthreads();

        // interior self-write from f32 registers (overlaps tid0's poll)
        if (act) smP[g * PSTRIDE + ctr2] = (float2v){smv[0], smv[1]};

        // ---- neighbor-only epoch sync (tag-encoded, poison-robust) ----
        if (tid == 0) {
            const unsigned seq = (unsigned)(it + 1);
            if (it > 0)
                __hip_atomic_store(&bar[EPW(bid)], EPTAG | seq,
                                   __ATOMIC_RELAXED, __HIP_MEMORY_SCOPE_AGENT);
            unsigned mn;
            unsigned spins = 0;
            do {
                mn = 0xFFFFu;
                #pragma unroll
                for (int k = 0; k < 8; ++k) {
                    const unsigned w = __hip_atomic_load(&bar[EPW(nb[k])],
                                                         __ATOMIC_RELAXED, __HIP_MEMORY_SCOPE_AGENT);
                    const unsigned e = ep_decode(w);
                    mn = (e < mn) ? e : mn;
                }
                if (mn < seq) {
                    __builtin_amdgcn_s_sleep(1);
                    if (++spins > (1u << 22)) break;   // watchdog (~0.2s)
                }
            } while (mn < seq);
        }
        __syncthreads();

        // ---- stage: ring from gsm, 10 planes x 156 elems (f16 -> f32 once) ----
        const unsigned* gsrc = ((it & 1) ? gsmB : gsmA);
        #pragma unroll
        for (int k2 = 0; k2 < 2; ++k2) {
            const int e = tid + NTHR * k2;
            if (e < NG * NRING) {
                const int sg = e / NRING, re = e - sg * NRING;
                int hr, hc;
                if (re < 48)        { hr = re >> 4;               hc = re & 15; }
                else if (re < 96)   { hr = 13 + ((re - 48) >> 4); hc = (re - 48) & 15; }
                else                { const int t2 = re - 96; hr = 3 + t2 / 6;
                                      const int s = t2 % 6;   hc = (s < 3) ? s : s + 10; }
                const int yi = ti0 - SPAN + hr, xj = tj0 - SPAN + hc;
                float2v fv = (float2v){0.f, 0.f};
                if ((unsigned)yi < HH && (unsigned)xj < WW) {
                    const unsigned raw =
                        __hip_atomic_load(&gsrc[sg * NPIX + yi * WW + xj],
                                          __ATOMIC_RELAXED, __HIP_MEMORY_SCOPE_AGENT);
                    half2f hv; __builtin_memcpy(&hv, &raw, 4);
                    fv = (float2v){(float)hv.x, (float)hv.y};
                }
                smP[sg * PSTRIDE + hr * LCP2 + hc] = fv;
            }
        }
        __syncthreads();

        // ---- 49 taps: 2x ds_read_b64 (2-way free) + 3 v_pk_fma_f32 each ----
        float2v sA2 = (float2v){0.f,0.f}, b02 = (float2v){0.f,0.f}, b12 = (float2v){0.f,0.f};
        if (act) {
            const float2v* pl = smP + g * PSTRIDE + ctr2;
            #pragma unroll
            for (int t = 0; t < 49; ++t) {
                const int dx = t / 7 - SPAN, dy = t % 7 - SPAN;
                const float2v f = pl[dx * LCP2 + dy];
                const float2v w = wbF[t * NPXT + px];
                sA2 += WSPC[t] * f;
                b02 += w.x * f;
                b12 += w.y * f;
            }
        }
        const float sAv[2] = {sA2.x, sA2.y};
        const float b0a[2] = {b02.x, b02.y};
        const float b1a[2] = {b12.x, b12.y};

        float q0v[2], q1v[2];
        if (isdiag) {
            if (act) {
                #pragma unroll
                for (int i = 0; i < 2; ++i) {
                    const float sAn = sAv[i] * snI;
                    const float b0n = b0a[i] * bnI0;
                    const float b1x = b1a[i] * bnI1;
                    q0v[i] = uv0[i] - dsv[i]*sAn - dbv[i]*b0n;
                    q1v[i] = uv1[i] - (dsv[i] + dbv[i]) + dsv[i]*sAn + dbv[i]*b1x;
                }
            }
        } else {
            __syncthreads();   // planes dead -> region becomes accF
            if (act) {
                #pragma unroll
                for (int i = 0; i < 2; ++i) {
                    accF[(2*g + i) * NPXT + px]      = sAv[i] * snI;
                    accF[(20 + 2*g + i) * NPXT + px] = b0a[i] * bnI0;
                    accF[(40 + 2*g + i) * NPXT + px] = b1a[i] * bnI1;
                }
            }
            __syncthreads();
            if (act) {
                float t1[2] = {0,0}, t2[2] = {0,0}, t3[2] = {0,0};
                #pragma unroll
                for (int cc = 0; cc < 20; ++cc) {
                    const float sv  = accF[cc * NPXT + px];
                    const float b0v = accF[(20 + cc) * NPXT + px];
                    const float b1v = accF[(40 + cc) * NPXT + px];
                    #pragma unroll
                    for (int i = 0; i < 2; ++i) {
                        const float* mk = Msh + (2*g + i) * 48;
                        t1[i] += mk[cc] * sv;
                        t2[i] += mk[20 + cc] * b0v;
                        t3[i] += mk[20 + cc] * b1v;
                    }
                }
                #pragma unroll
                for (int i = 0; i < 2; ++i) {
                    const float rs = Msh[(2*g + i) * 48 + 40];
                    q0v[i] = uv0[i] - t1[i] - t2[i];
                    q1v[i] = uv1[i] - rs + t1[i] + t3[i];
                }
            }
        }

        if (it == 4) {
            if (act) {
                #pragma unroll
                for (int i = 0; i < 2; ++i) {
                    const int ch = 2*g + i;
                    if (ch < NC) {
                        out[(size_t)gp * NC + ch]          = q0v[i];
                        out[((size_t)NPIX + gp) * NC + ch] = q1v[i];
                    }
                }
            }
        } else if (act) {
            // sm for iteration it+1: f32 in regs (interior) + f16 publish (halo)
            #pragma unroll
            for (int i = 0; i < 2; ++i) smv[i] = smx0(q0v[i], q1v[i]);
            half2f hp = {(_Float16)smv[0], (_Float16)smv[1]};
            unsigned u32; __builtin_memcpy(&u32, &hp, 4);
            unsigned* gdst = (((it + 1) & 1) ? gsmB : gsmA);
            __hip_atomic_store(&gdst[g * NPIX + gp], u32,
                               __ATOMIC_RELAXED, __HIP_MEMORY_SCOPE_AGENT);
        }
    }
}

extern "C" void kernel_launch(void* const* d_in, const int* in_sizes, int n_in,
                              void* d_out, int out_size, void* d_ws, size_t ws_size,
                              hipStream_t stream) {
    const float* u      = (const float*)d_in[0];
    const float* rgb    = (const float*)d_in[1];
    const float* sw     = (const float*)d_in[2];
    const float* bw     = (const float*)d_in[3];
    const float* compat = (const float*)d_in[4];
    float* out = (float*)d_out;

    unsigned* gsmA = (unsigned*)d_ws;                          // 10 planes x 25600 u32
    unsigned* gsmB = (unsigned*)((char*)d_ws + 1024000);
    unsigned* bar  = (unsigned*)((char*)d_ws + 2048000);       // epochs (tag-encoded)

    crf_kernel<<<dim3(WW/TC, HH/TR, 1), dim3(NTHR), 0, stream>>>(
        u, rgb, sw, bw, compat, gsmA, gsmB, bar, out);
}